// Round 5
// baseline (388.928 us; speedup 1.0000x reference)
//
#include <hip/hip_runtime.h>
#include <hip/hip_bf16.h>
#include <cstdint>
#include <cmath>

#define S_LEN 4096
#define DMODEL 2048
#define NH 16
#define NKV 4
#define HD 128
#define NQKV 3072  // 2048 Q + 512 K + 512 V

typedef unsigned short u16;
typedef unsigned int u32;
typedef __attribute__((ext_vector_type(8))) __bf16 bf16x8;
typedef __attribute__((ext_vector_type(4))) float f32x4;
typedef __attribute__((ext_vector_type(16))) float f32x16;
typedef __attribute__((ext_vector_type(4))) int i32x4;

__device__ __forceinline__ u16 f2bf(float f) {
  __bf16 h = (__bf16)f;  // RNE
  return __builtin_bit_cast(u16, h);
}
__device__ __forceinline__ float bf2f(u16 u) {
  return (float)__builtin_bit_cast(__bf16, u);
}
// pack two f32 -> u32 of two bf16 (lo=a, hi=b); scalar casts, compiler fuses
__device__ __forceinline__ u32 pk2(float a, float b) {
  return (u32)f2bf(a) | ((u32)f2bf(b) << 16);
}

__device__ __forceinline__ void gload16(const void* g, void* l) {
  __builtin_amdgcn_global_load_lds(
      (const __attribute__((address_space(1))) void*)g,
      (__attribute__((address_space(3))) void*)l, 16, 0, 0);
}

// ---------------- pack / convert ----------------
__global__ void k_f32_to_bf16(const float* __restrict__ src, u16* __restrict__ dst, int n4) {
  int i = blockIdx.x * blockDim.x + threadIdx.x;
  if (i < n4) {
    float4 v = reinterpret_cast<const float4*>(src)[i];
    ushort4 o = make_ushort4(f2bf(v.x), f2bf(v.y), f2bf(v.z), f2bf(v.w));
    reinterpret_cast<ushort4*>(dst)[i] = o;
  }
}

// dst[n][k] = bf16(src[k][n])
__global__ void k_transpose_f32_bf16(const float* __restrict__ src, int srcStride,
                                     u16* __restrict__ dst, int dstStride) {
  __shared__ float tile[32][33];
  int n0 = blockIdx.x * 32, k0 = blockIdx.y * 32;
  int tx = threadIdx.x, ty = threadIdx.y;  // 32 x 8
#pragma unroll
  for (int r = 0; r < 32; r += 8)
    tile[ty + r][tx] = src[(size_t)(k0 + ty + r) * srcStride + n0 + tx];
  __syncthreads();
#pragma unroll
  for (int r = 0; r < 32; r += 8)
    dst[(size_t)(n0 + ty + r) * dstStride + k0 + tx] = f2bf(tile[tx][ty + r]);
}

__global__ void k_transpose_bf16(const u16* __restrict__ src, int srcStride,
                                 u16* __restrict__ dst, int dstStride) {
  __shared__ u16 tile[32][33];
  int n0 = blockIdx.x * 32, k0 = blockIdx.y * 32;
  int tx = threadIdx.x, ty = threadIdx.y;  // 32 x 8
#pragma unroll
  for (int r = 0; r < 32; r += 8)
    tile[ty + r][tx] = src[(size_t)(k0 + ty + r) * srcStride + n0 + tx];
  __syncthreads();
#pragma unroll
  for (int r = 0; r < 32; r += 8)
    dst[(size_t)(n0 + ty + r) * dstStride + k0 + tx] = tile[tx][ty + r];
}

// ---------------- RoPE ----------------
// Q gets 1/sqrt(HD) * LOG2E folded in (softmax runs in exp2 domain).
__global__ void k_rope(const u16* __restrict__ qkv, const int* __restrict__ pos_ids,
                       u16* __restrict__ Qb, u16* __restrict__ Kb) {
  int s = blockIdx.x;
  float pos = (float)pos_ids[s];
  const u16* row = qkv + (size_t)s * NQKV;
  const float L2B = 13.287712379549449f;  // log2(10000)
  const float QSCALE = 0.08838834764831845f * 1.4426950408889634f;
  for (int c = threadIdx.x; c < DMODEL + NKV * HD; c += blockDim.x) {
    int d = c & 127;
    int dh = d & 63;
    float invf = exp2f(-(float)dh * (L2B / 64.0f));
    float ang = pos * invf;
    float cv = cosf(ang), sv = sinf(ang);
    float x = bf2f(row[c]);
    float xp = bf2f(row[c ^ 64]);
    float rot = (d < 64) ? -xp : xp;
    float out = x * cv + rot * sv;
    if (c < DMODEL) {
      int h = c >> 7;
      out *= QSCALE;
      Qb[((size_t)h * S_LEN + s) * HD + d] = f2bf(out);
    } else {
      int kvh = (c - DMODEL) >> 7;
      Kb[((size_t)kvh * S_LEN + s) * HD + d] = f2bf(out);
    }
  }
}

// ---------------- m97-style 128x128 GEMM, B^T operand ----------------
template <int OUT_BF16>
__global__ __launch_bounds__(256) void k_gemm_bt(const u16* __restrict__ A,
                                                 const u16* __restrict__ BT,
                                                 void* __restrict__ C, int M, int N, int K) {
  __shared__ __align__(16) u16 As[128 * 32];
  __shared__ __align__(16) u16 Bs[128 * 32];
  const int tid = threadIdx.x, wave = tid >> 6, lane = tid & 63;
  const int fr = lane & 15, fq = lane >> 4;
  const int rowBase = blockIdx.y * 128, colBase = blockIdx.x * 128;
  const int wr = wave >> 1, wc = wave & 1;
  f32x4 acc[4][4] = {};
  const int nk = K >> 5;
  for (int kt = 0; kt < nk; ++kt) {
    const int k0 = kt << 5;
#pragma unroll
    for (int p = 0; p < 2; ++p) {
      int cbase = p * 256 + wave * 64;
      int chunk = cbase + lane;
      int r = chunk >> 2, cb = chunk & 3;
      gload16(A + (size_t)(rowBase + r) * K + k0 + cb * 8, (char*)As + cbase * 16);
      gload16(BT + (size_t)(colBase + r) * K + k0 + cb * 8, (char*)Bs + cbase * 16);
    }
    __syncthreads();
    bf16x8 a[4], b[4];
#pragma unroll
    for (int m = 0; m < 4; ++m)
      a[m] = *reinterpret_cast<const bf16x8*>(&As[(wr * 64 + m * 16 + fr) * 32 + fq * 8]);
#pragma unroll
    for (int n = 0; n < 4; ++n)
      b[n] = *reinterpret_cast<const bf16x8*>(&Bs[(wc * 64 + n * 16 + fr) * 32 + fq * 8]);
#pragma unroll
    for (int m = 0; m < 4; ++m)
#pragma unroll
      for (int n = 0; n < 4; ++n)
        acc[m][n] = __builtin_amdgcn_mfma_f32_16x16x32_bf16(a[m], b[n], acc[m][n], 0, 0, 0);
    __syncthreads();
  }
#pragma unroll
  for (int m = 0; m < 4; ++m) {
    int row0 = rowBase + wr * 64 + m * 16 + fq * 4;
#pragma unroll
    for (int n = 0; n < 4; ++n) {
      int col = colBase + wc * 64 + n * 16 + fr;
#pragma unroll
      for (int j = 0; j < 4; ++j) {
        if (OUT_BF16)
          ((u16*)C)[(size_t)(row0 + j) * N + col] = f2bf(acc[m][n][j]);
        else
          ((float*)C)[(size_t)(row0 + j) * N + col] = acc[m][n][j];
      }
    }
  }
}

// ---------------- flash attention (causal, GQA) ----------------
// m214-style: 4 waves x 32 q (QBLK=128), 32x32x16 MFMA, swapped QK^T so each
// lane-pair owns one q-row; softmax in-lane + 1 shfl_xor(32); P built
// in-register (pack + shfl_xor + select); PV swapped too (O^T). K,V dbuf in
// LDS, conflict-free XOR swizzles. All cross-lane via __shfl_xor (no asm).
// Qb [H][S][HD] (pre-scaled by 1/sqrt(HD)*LOG2E), Kb [KV][S][HD],
// VT [KV][HD][S], AO [S][H*HD]
__device__ __forceinline__ void stage_kv4(const u16* __restrict__ Kbk,
                                          const u16* __restrict__ VTk, int kb,
                                          char* KsB, char* VsB, int wave, int lane) {
#pragma unroll
  for (int p = 0; p < 4; ++p) {
    int cbase = p * 256 + wave * 64;
    int c = cbase + lane;
    int r = c >> 4, cb = c & 15;                 // K: [64 k][16 chunks]
    gload16(Kbk + (size_t)(kb + r) * HD + (size_t)((cb ^ (r & 15)) * 8), KsB + cbase * 16);
    int d = c >> 3, vb = c & 7;                  // V: [128 d][8 chunks]
    gload16(VTk + (size_t)d * S_LEN + kb + (vb ^ (d & 7)) * 8, VsB + cbase * 16);
  }
}

__global__ __launch_bounds__(256) void k_attn(const u16* __restrict__ Qb,
                                              const u16* __restrict__ Kb,
                                              const u16* __restrict__ VT,
                                              u16* __restrict__ AO) {
  __shared__ __align__(16) u16 Ks[2][64 * 128];  // [k][d], ^(k&15) chunk swizzle
  __shared__ __align__(16) u16 Vs[2][128 * 64];  // [d][k], ^(d&7) chunk swizzle
  const int h = blockIdx.x;
  const int qidx = blockIdx.y;
  // complementary-work pairing: blocks bid, bid+256 co-reside per CU.
  const int qt = (qidx < 16) ? (31 - qidx) : (qidx - 16);
  const int kv = h >> 2;
  const int tid = threadIdx.x, wave = tid >> 6, lane = tid & 63;
  const int ql = lane & 31, hi = lane >> 5;
  const int qrow0 = qt * 128;
  const int qg0w = qrow0 + wave * 32;  // wave's first q row
  const int qglob = qg0w + ql;         // this lane's q row
  const float DEFER_THR = 11.541560327111707f;  // 8 * log2(e)

  const u16* Kbk = Kb + (size_t)kv * S_LEN * HD;
  const u16* VTk = VT + (size_t)kv * HD * S_LEN;

  int buf = 0;
  stage_kv4(Kbk, VTk, 0, (char*)Ks[0], (char*)Vs[0], wave, lane);

  // Q as B-operand frags: lane(ql,hi) holds Q[qglob][t*16 + hi*8 + e]
  bf16x8 qf[8];
  {
    const u16* qp = Qb + ((size_t)h * S_LEN + qglob) * HD;
#pragma unroll
    for (int t = 0; t < 8; ++t)
      qf[t] = *reinterpret_cast<const bf16x8*>(qp + t * 16 + hi * 8);
  }
  f32x16 o[4] = {};  // O^T: lane(ql=q,hi) holds O[q][d0*32 + (r&3)+8*(r>>2)+4*hi]
  float m = -INFINITY, l = 0.f;

  __syncthreads();  // tile 0 staged

  const int nkt = 2 * qt + 2;
  for (int kt = 0; kt < nkt; ++kt) {
    if (kt + 1 < nkt)
      stage_kv4(Kbk, VTk, (kt + 1) * 64, (char*)Ks[buf ^ 1], (char*)Vs[buf ^ 1], wave, lane);
    const int kb = kt * 64;
    if (kb <= qg0w + 31) {  // wave has >=1 unmasked column in this tile
      const char* Kc = (const char*)Ks[buf];
      const char* Vc = (const char*)Vs[buf];

      // S^T = mfma(A=K rows, B=Q): st0 = k 0..31, st1 = k 32..63 of the tile
      f32x16 st0 = {}, st1 = {};
#pragma unroll
      for (int t = 0; t < 8; ++t) {
        int ch = (2 * t + hi) ^ (ql & 15);
        bf16x8 kf0 = *reinterpret_cast<const bf16x8*>(Kc + ql * 256 + ch * 16);
        bf16x8 kf1 = *reinterpret_cast<const bf16x8*>(Kc + (32 + ql) * 256 + ch * 16);
        st0 = __builtin_amdgcn_mfma_f32_32x32x16_bf16(kf0, qf[t], st0, 0, 0, 0);
        st1 = __builtin_amdgcn_mfma_f32_32x32x16_bf16(kf1, qf[t], st1, 0, 0, 0);
      }
      // causal mask: lane reg r holds k_local = (r&3)+8*(r>>2)+4*hi
      if (kb + 63 > qg0w) {
#pragma unroll
        for (int r = 0; r < 16; ++r) {
          int kl = (r & 3) + 8 * (r >> 2) + 4 * hi;
          if (kb + kl > qglob) st0[r] = -1e30f;
          if (kb + 32 + kl > qglob) st1[r] = -1e30f;
        }
      }
      // row max: in-lane tree over 32 values, then lane-pair combine (xor 32)
      float mx[16];
#pragma unroll
      for (int r = 0; r < 16; ++r) mx[r] = fmaxf(st0[r], st1[r]);
#pragma unroll
      for (int s = 8; s > 0; s >>= 1)
#pragma unroll
        for (int r = 0; r < 16; ++r)
          if (r < s) mx[r] = fmaxf(mx[r], mx[r + s]);
      float tmax = fmaxf(mx[0], __shfl_xor(mx[0], 32));
      // defer-max (T13)
      if (__any(tmax - m > DEFER_THR)) {
        float mn = fmaxf(m, tmax);
        float corr = exp2f(m - mn);
        m = mn;
        l *= corr;
#pragma unroll
        for (int d0 = 0; d0 < 4; ++d0) o[d0] *= corr;
      }
      // P = exp2(S - m); in-lane sum + lane-pair combine
      float sm[16];
#pragma unroll
      for (int r = 0; r < 16; ++r) {
        st0[r] = exp2f(st0[r] - m);
        st1[r] = exp2f(st1[r] - m);
        sm[r] = st0[r] + st1[r];
      }
#pragma unroll
      for (int s = 8; s > 0; s >>= 1)
#pragma unroll
        for (int r = 0; r < 16; ++r)
          if (r < s) sm[r] += sm[r + s];
      l += sm[0] + __shfl_xor(sm[0], 32);

      // P -> bf16 B-frags in-register: pack pairs, swap halves via shfl_xor(32),
      // select per hi. Frag slot (hi,e) holds P[q][kc*16 + hi*8 + e].
      bf16x8 pa[4];
#pragma unroll
      for (int kc = 0; kc < 4; ++kc) {
        int rb = 8 * (kc & 1);
        u32 w0, w1, w2, w3;
        if (kc < 2) {
          w0 = pk2(st0[rb + 0], st0[rb + 1]);
          w1 = pk2(st0[rb + 2], st0[rb + 3]);
          w2 = pk2(st0[rb + 4], st0[rb + 5]);
          w3 = pk2(st0[rb + 6], st0[rb + 7]);
        } else {
          w0 = pk2(st1[rb + 0], st1[rb + 1]);
          w1 = pk2(st1[rb + 2], st1[rb + 3]);
          w2 = pk2(st1[rb + 4], st1[rb + 5]);
          w3 = pk2(st1[rb + 6], st1[rb + 7]);
        }
        u32 xw0 = (u32)__shfl_xor((int)w0, 32);
        u32 xw1 = (u32)__shfl_xor((int)w1, 32);
        u32 xw2 = (u32)__shfl_xor((int)w2, 32);
        u32 xw3 = (u32)__shfl_xor((int)w3, 32);
        i32x4 pw;
        pw[0] = (int)(hi ? xw2 : w0);
        pw[1] = (int)(hi ? xw3 : w1);
        pw[2] = (int)(hi ? w2 : xw0);
        pw[3] = (int)(hi ? w3 : xw1);
        pa[kc] = __builtin_bit_cast(bf16x8, pw);
      }
      // O^T += mfma(A=V^T rows, B=P^T)
#pragma unroll
      for (int d0 = 0; d0 < 4; ++d0) {
        int dr = d0 * 32 + ql;
#pragma unroll
        for (int kc = 0; kc < 4; ++kc) {
          int ch = (2 * kc + hi) ^ (ql & 7);
          bf16x8 vf = *reinterpret_cast<const bf16x8*>(Vc + dr * 128 + ch * 16);
          o[d0] = __builtin_amdgcn_mfma_f32_32x32x16_bf16(vf, pa[kc], o[d0], 0, 0, 0);
        }
      }
    }
    __syncthreads();  // next tile staged; buf safe to flip
    buf ^= 1;
  }

  // epilogue: normalize, pack bf16 pairs, store AO[q][h*HD + d]
  {
    float inv = 1.0f / l;
    u16* aoRow = AO + (size_t)qglob * DMODEL + h * HD;
#pragma unroll
    for (int d0 = 0; d0 < 4; ++d0)
#pragma unroll
      for (int rp = 0; rp < 8; ++rp) {
        int reg = rp * 2;
        int d = d0 * 32 + (reg & 3) + 8 * (reg >> 2) + 4 * hi;
        u32 w = pk2(o[d0][reg] * inv, o[d0][reg + 1] * inv);
        *reinterpret_cast<u32*>(aoRow + d) = w;
      }
  }
}

// ---------------- launch ----------------
extern "C" void kernel_launch(void* const* d_in, const int* in_sizes, int n_in,
                              void* d_out, int out_size, void* d_ws, size_t ws_size,
                              hipStream_t stream) {
  const float* hidden = (const float*)d_in[0];
  const float* Wq = (const float*)d_in[1];
  const float* Wk = (const float*)d_in[2];
  const float* Wv = (const float*)d_in[3];
  const float* Wo = (const float*)d_in[4];
  // d_in[5] = attention_mask: causal, applied analytically (unused)
  const int* pos_ids = (const int*)d_in[6];
  float* out = (float*)d_out;

  char* ws = (char*)d_ws;
  u16* Xb   = (u16*)(ws);                               // [4096][2048]   16MB
  u16* Wt   = (u16*)(ws + (16ull << 20));               // [3072][2048]   12MB
  u16* WoT  = (u16*)(ws + (28ull << 20));               // [2048][2048]    8MB
  u16* QKVb = (u16*)(ws + (36ull << 20));               // [4096][3072]   24MB
  u16* Qb   = (u16*)(ws + (60ull << 20));               // [16][4096][128] 16MB
  u16* Kb   = (u16*)(ws + (76ull << 20));               // [4][4096][128]   4MB
  u16* VT   = (u16*)(ws + (80ull << 20));               // [4][128][4096]   4MB
  u16* AO   = QKVb;  // alias: QKVb fully consumed before attention writes AO

  dim3 tb(32, 8);
  k_f32_to_bf16<<<dim3((S_LEN * DMODEL / 4) / 256), dim3(256), 0, stream>>>(
      hidden, Xb, S_LEN * DMODEL / 4);
  k_transpose_f32_bf16<<<dim3(64, 64), tb, 0, stream>>>(Wq, 2048, Wt, 2048);
  k_transpose_f32_bf16<<<dim3(16, 64), tb, 0, stream>>>(Wk, 512, Wt + (size_t)2048 * 2048, 2048);
  k_transpose_f32_bf16<<<dim3(16, 64), tb, 0, stream>>>(Wv, 512, Wt + (size_t)2560 * 2048, 2048);
  k_transpose_f32_bf16<<<dim3(64, 64), tb, 0, stream>>>(Wo, 2048, WoT, 2048);

  k_gemm_bt<1><<<dim3(24, 32), 256, 0, stream>>>(Xb, Wt, QKVb, S_LEN, NQKV, DMODEL);

  k_rope<<<dim3(S_LEN), 256, 0, stream>>>(QKVb, pos_ids, Qb, Kb);
  k_transpose_bf16<<<dim3(16, 128), tb, 0, stream>>>(QKVb + 2560, NQKV, VT, S_LEN);

  k_attn<<<dim3(NH, 32), 256, 0, stream>>>(Qb, Kb, VT, AO);

  k_gemm_bt<0><<<dim3(16, 32), 256, 0, stream>>>(AO, WoT, out, S_LEN, DMODEL, DMODEL);
}